// Round 12
// baseline (459.673 us; speedup 1.0000x reference)
//
#include <hip/hip_runtime.h>
#include <hip/hip_bf16.h>

#define BB 8
#define NN 2048
#define FF 128

typedef __bf16 bf16x8 __attribute__((ext_vector_type(8)));
typedef float f32x4 __attribute__((ext_vector_type(4)));
typedef float f32x16 __attribute__((ext_vector_type(16)));

__device__ __forceinline__ void gload_lds16(const void* g, void* l) {
    __builtin_amdgcn_global_load_lds(
        (const __attribute__((address_space(1))) unsigned int*)g,
        (__attribute__((address_space(3))) unsigned int*)l, 16, 0, 0);
}

// ---------------------------------------------------------------------------
// Kernel A: unchanged (refcheck-proven).
// ---------------------------------------------------------------------------
__global__ __launch_bounds__(256) void wh_kernel(
    const float* __restrict__ h, const float* __restrict__ W,
    const float* __restrict__ a, __bf16* __restrict__ fragB,
    float* __restrict__ srcg, float* __restrict__ dstg)
{
    __shared__ float  s_h[32][132];
    __shared__ __bf16 s_wh[32][132];
    __shared__ float  s_s[2][32];
    __shared__ float  s_d[2][32];

    const int bid = blockIdx.x;
    const int b   = bid >> 6;
    const int J   = bid & 63;
    const int r0  = J * 32;
    const int t   = threadIdx.x;
    const int w   = t >> 6;
    const int l   = t & 63;
    const int itile = w & 1;
    const int fh    = w >> 1;
    const int g     = l >> 4;
    const int c16   = l & 15;

#pragma unroll
    for (int i = 0; i < 4; ++i) {
        const int idx = t + i * 256;
        const int r   = idx >> 5;
        const int c4  = idx & 31;
        *(f32x4*)&s_h[r][c4 * 4] =
            *(const f32x4*)(h + (size_t)(b * NN + r0 + r) * FF + c4 * 4);
    }
    __syncthreads();

    const float* hrow = &s_h[itile * 16 + c16][0];
    f32x4 acc[4] = {};

#pragma unroll
    for (int kt = 0; kt < 4; ++kt) {
        const int k0 = kt * 32 + g * 8;
        f32x4 h0 = *(const f32x4*)(hrow + k0);
        f32x4 h1 = *(const f32x4*)(hrow + k0 + 4);
        bf16x8 af;
        af[0]=(__bf16)h0[0]; af[1]=(__bf16)h0[1]; af[2]=(__bf16)h0[2]; af[3]=(__bf16)h0[3];
        af[4]=(__bf16)h1[0]; af[5]=(__bf16)h1[1]; af[6]=(__bf16)h1[2]; af[7]=(__bf16)h1[3];
#pragma unroll
        for (int ft = 0; ft < 4; ++ft) {
            const int c = (fh * 4 + ft) * 16 + c16;
            bf16x8 bf;
#pragma unroll
            for (int e = 0; e < 8; ++e) bf[e] = (__bf16)W[(k0 + e) * FF + c];
            acc[ft] = __builtin_amdgcn_mfma_f32_16x16x32_bf16(af, bf, acc[ft], 0, 0, 0);
        }
    }

    float a1v[4], a2v[4];
#pragma unroll
    for (int ft = 0; ft < 4; ++ft) {
        const int c = (fh * 4 + ft) * 16 + c16;
        a1v[ft] = a[c];
        a2v[ft] = a[FF + c];
    }
#pragma unroll
    for (int r = 0; r < 4; ++r) {
        float s = 0.f, d2 = 0.f;
#pragma unroll
        for (int ft = 0; ft < 4; ++ft) {
            s  += acc[ft][r] * a1v[ft];
            d2 += acc[ft][r] * a2v[ft];
        }
#pragma unroll
        for (int m = 1; m <= 8; m <<= 1) {
            s  += __shfl_xor(s,  m);
            d2 += __shfl_xor(d2, m);
        }
        if (c16 == 0) {
            s_s[fh][itile * 16 + g * 4 + r] = s;
            s_d[fh][itile * 16 + g * 4 + r] = d2;
        }
    }

#pragma unroll
    for (int ft = 0; ft < 4; ++ft)
#pragma unroll
        for (int r = 0; r < 4; ++r)
            s_wh[itile * 16 + g * 4 + r][(fh * 4 + ft) * 16 + c16] = (__bf16)acc[ft][r];

    __syncthreads();

#pragma unroll
    for (int e2 = 0; e2 < 2; ++e2) {
        const int ent  = t + e2 * 256;
        const int tile = ent >> 6;
        const int jl   = tile >> 2;
        const int ft   = tile & 3;
        const int lE   = ent & 63;
        const int rowE = jl * 16 + (lE >> 5) * 8;
        const int colE = ft * 32 + (lE & 31);
        bf16x8 v;
#pragma unroll
        for (int ee = 0; ee < 8; ++ee) v[ee] = s_wh[rowE + ee][colE];
        *(bf16x8*)(fragB + (((size_t)(b * 128 + J * 2 + jl) * 4 + ft) * 64 + lE) * 8) = v;
    }

    if (t < 32) {
        srcg[b * NN + r0 + t] = s_s[0][t] + s_s[1][t];
        dstg[b * NN + r0 + t] = s_d[0][t] + s_d[1][t];
    }
}

// ===========================================================================
// ABLATION ROUND. All variants share v8's geometry/LDS/occupancy exactly.
// FULL is v8-verbatim logic wrapped in a 3-rep loop (last rep = real output).
// Ablations keep all compute live (acc/psum -> scratch, block 0 only).
// ===========================================================================

#define GEOM                                                                  \
    const int bid0 = blockIdx.x;                                              \
    const int bid  = (bid0 & 7) * 64 + (bid0 >> 3);                           \
    const int b    = bid >> 6;                                                \
    const int I0   = (bid & 63) * 32;                                         \
    const int t    = threadIdx.x;                                             \
    const int q    = t >> 6;                                                  \
    const int l    = t & 63;                                                  \
    const int r31  = l & 31;                                                  \
    const int hi   = l >> 5;

#define EXPB(MASKEXPR)                                                        \
        bf16x8 af;                                                            \
        _Pragma("unroll")                                                     \
        for (int e = 0; e < 8; ++e) {                                         \
            float x = sv + dv[e];                                             \
            x = fmaxf(x, 0.2f * x);                                           \
            float p = __expf(x);                                              \
            p = (MASKEXPR) ? p : 0.f;                                         \
            psum += p;                                                        \
            af[e] = (__bf16)p;                                                \
        }

// ---------------- FULL (rep 3, real output) ----------------
__global__ __launch_bounds__(256, 2) void attn_full(
    const int* __restrict__ adj, const __bf16* __restrict__ fragB,
    const float* __restrict__ srcg, const float* __restrict__ dstg,
    float* __restrict__ out)
{
    __shared__ char s_all[74240];
    GEOM
    char* awave = s_all + q * 8192;
    char* fwave = s_all + 32768 + q * 8192;
    char* dstw  = s_all + 65536 + q * 2048;
    float* s_ps = (float*)(s_all + 73728);

    const float sv = srcg[b * NN + I0 + r31];
    asm volatile("s_waitcnt vmcnt(0) lgkmcnt(0)" ::: "memory");

    const char* aSrc = (const char*)adj
        + ((size_t)(b * NN + I0 + r31) * NN + q * 512) * 4 + hi * 32;
    const char* fBase = (const char*)fragB
        + (size_t)(b * 128 + q * 32) * 4096 + (size_t)l * 16;
    const char* dSrc = (const char*)(dstg + (size_t)b * NN + q * 512) + l * 16;

#define ISSUE_A(ki_, sl_) {                                                   \
        const char* pa_ = aSrc + (size_t)(ki_) * 64;                          \
        gload_lds16(pa_,      awave + (sl_) * 2048 + l * 16);                 \
        gload_lds16(pa_ + 16, awave + (sl_) * 2048 + 1024 + l * 16); }
#define ISSUE_F(ki_, sl_) {                                                   \
        const char* pf_ = fBase + (size_t)(ki_) * 4096;                       \
        char* fd_ = fwave + (sl_) * 4096 + l * 16;                            \
        gload_lds16(pf_,        fd_);                                         \
        gload_lds16(pf_ + 1024, fd_ + 1024);                                  \
        gload_lds16(pf_ + 2048, fd_ + 2048);                                  \
        gload_lds16(pf_ + 3072, fd_ + 3072); }

    f32x16 acc0, acc1, acc2, acc3;
    float psum;

#pragma unroll 1
    for (int rep = 0; rep < 3; ++rep) {
        acc0 = f32x16{}; acc1 = f32x16{}; acc2 = f32x16{}; acc3 = f32x16{};
        psum = 0.f;
        gload_lds16(dSrc,        dstw + l * 16);
        gload_lds16(dSrc + 1024, dstw + 1024 + l * 16);
        ISSUE_A(0, 0);
        ISSUE_F(0, 0);
        ISSUE_A(1, 1);

#pragma unroll 4
        for (int kt = 0; kt < 32; ++kt) {
            const int kF = (kt + 1 < 32) ? kt + 1 : 31;
            const int kA = (kt + 2 < 32) ? kt + 2 : 31;
            ISSUE_F(kF, (kt + 1) & 1);
            ISSUE_A(kA, (kt + 2) & 3);
            asm volatile("s_waitcnt vmcnt(8)" ::: "memory");

            const char* asl = awave + (kt & 3) * 2048 + l * 16;
            const int4 A0 = *(const int4*)(asl);
            const int4 A1 = *(const int4*)(asl + 1024);
            const f32x4 d0 = *(const f32x4*)(dstw + kt * 64 + hi * 32);
            const f32x4 d1 = *(const f32x4*)(dstw + kt * 64 + hi * 32 + 16);
            const int   am[8] = {A0.x, A0.y, A0.z, A0.w, A1.x, A1.y, A1.z, A1.w};
            const float dv[8] = {d0[0], d0[1], d0[2], d0[3], d1[0], d1[1], d1[2], d1[3]};
            EXPB(am[e] > 0)
            const char* fsl = fwave + (kt & 1) * 4096 + l * 16;
            const bf16x8 b0 = *(const bf16x8*)(fsl);
            const bf16x8 b1 = *(const bf16x8*)(fsl + 1024);
            const bf16x8 b2 = *(const bf16x8*)(fsl + 2048);
            const bf16x8 b3 = *(const bf16x8*)(fsl + 3072);
            acc0 = __builtin_amdgcn_mfma_f32_32x32x16_bf16(af, b0, acc0, 0, 0, 0);
            acc1 = __builtin_amdgcn_mfma_f32_32x32x16_bf16(af, b1, acc1, 0, 0, 0);
            acc2 = __builtin_amdgcn_mfma_f32_32x32x16_bf16(af, b2, acc2, 0, 0, 0);
            acc3 = __builtin_amdgcn_mfma_f32_32x32x16_bf16(af, b3, acc3, 0, 0, 0);
        }
        asm volatile("s_waitcnt vmcnt(0)" ::: "memory");
    }
#undef ISSUE_A
#undef ISSUE_F

    psum += __shfl_xor(psum, 32);
    if (l < 32) s_ps[q * 32 + l] = psum;

    __syncthreads();
    float* comb = (float*)s_all;
    {
        float* cb = comb + ((q * 4 + 0) * 64 + l) * 17;
#pragma unroll
        for (int r = 0; r < 16; ++r) cb[r] = acc0[r];
        cb = comb + ((q * 4 + 1) * 64 + l) * 17;
#pragma unroll
        for (int r = 0; r < 16; ++r) cb[r] = acc1[r];
        cb = comb + ((q * 4 + 2) * 64 + l) * 17;
#pragma unroll
        for (int r = 0; r < 16; ++r) cb[r] = acc2[r];
        cb = comb + ((q * 4 + 3) * 64 + l) * 17;
#pragma unroll
        for (int r = 0; r < 16; ++r) cb[r] = acc3[r];
    }
    __syncthreads();

    f32x16 tot;
#pragma unroll
    for (int r = 0; r < 16; ++r)
        tot[r] = comb[((0 * 4 + q) * 64 + l) * 17 + r]
               + comb[((1 * 4 + q) * 64 + l) * 17 + r]
               + comb[((2 * 4 + q) * 64 + l) * 17 + r]
               + comb[((3 * 4 + q) * 64 + l) * 17 + r];

    const float dtot = s_ps[0 * 32 + r31] + s_ps[1 * 32 + r31]
                     + s_ps[2 * 32 + r31] + s_ps[3 * 32 + r31];
    const float rin  = 1.f / dtot;

#pragma unroll
    for (int r = 0; r < 16; ++r) {
        const int row  = (r & 3) + 8 * (r >> 2) + 4 * hi;
        const float dv2 = __shfl(rin, row);
        out[(size_t)(b * NN + I0 + row) * FF + q * 32 + r31] = tot[r] * dv2;
    }
}

// ---------------- NOADJ (frag + skeleton; mask = 1), rep 10 ----------------
__global__ __launch_bounds__(256, 2) void attn_noadj(
    const __bf16* __restrict__ fragB, const float* __restrict__ srcg,
    const float* __restrict__ dstg, float* __restrict__ scr)
{
    __shared__ char s_all[74240];
    GEOM
    char* fwave = s_all + 32768 + q * 8192;
    char* dstw  = s_all + 65536 + q * 2048;

    const float sv = srcg[b * NN + I0 + r31];
    asm volatile("s_waitcnt vmcnt(0) lgkmcnt(0)" ::: "memory");

    const char* fBase = (const char*)fragB
        + (size_t)(b * 128 + q * 32) * 4096 + (size_t)l * 16;
    const char* dSrc = (const char*)(dstg + (size_t)b * NN + q * 512) + l * 16;

#define ISSUE_F(ki_, sl_) {                                                   \
        const char* pf_ = fBase + (size_t)(ki_) * 4096;                       \
        char* fd_ = fwave + (sl_) * 4096 + l * 16;                            \
        gload_lds16(pf_,        fd_);                                         \
        gload_lds16(pf_ + 1024, fd_ + 1024);                                  \
        gload_lds16(pf_ + 2048, fd_ + 2048);                                  \
        gload_lds16(pf_ + 3072, fd_ + 3072); }

    f32x16 acc0 = {}, acc1 = {}, acc2 = {}, acc3 = {};
    float psum = 0.f;

#pragma unroll 1
    for (int rep = 0; rep < 10; ++rep) {
        gload_lds16(dSrc,        dstw + l * 16);
        gload_lds16(dSrc + 1024, dstw + 1024 + l * 16);
        ISSUE_F(0, 0);
#pragma unroll 4
        for (int kt = 0; kt < 32; ++kt) {
            const int kF = (kt + 1 < 32) ? kt + 1 : 31;
            ISSUE_F(kF, (kt + 1) & 1);
            asm volatile("s_waitcnt vmcnt(4)" ::: "memory");
            const f32x4 d0 = *(const f32x4*)(dstw + kt * 64 + hi * 32);
            const f32x4 d1 = *(const f32x4*)(dstw + kt * 64 + hi * 32 + 16);
            const float dv[8] = {d0[0], d0[1], d0[2], d0[3], d1[0], d1[1], d1[2], d1[3]};
            EXPB(1)
            const char* fsl = fwave + (kt & 1) * 4096 + l * 16;
            const bf16x8 b0 = *(const bf16x8*)(fsl);
            const bf16x8 b1 = *(const bf16x8*)(fsl + 1024);
            const bf16x8 b2 = *(const bf16x8*)(fsl + 2048);
            const bf16x8 b3 = *(const bf16x8*)(fsl + 3072);
            acc0 = __builtin_amdgcn_mfma_f32_32x32x16_bf16(af, b0, acc0, 0, 0, 0);
            acc1 = __builtin_amdgcn_mfma_f32_32x32x16_bf16(af, b1, acc1, 0, 0, 0);
            acc2 = __builtin_amdgcn_mfma_f32_32x32x16_bf16(af, b2, acc2, 0, 0, 0);
            acc3 = __builtin_amdgcn_mfma_f32_32x32x16_bf16(af, b3, acc3, 0, 0, 0);
        }
        asm volatile("s_waitcnt vmcnt(0)" ::: "memory");
    }
#undef ISSUE_F

    psum += __shfl_xor(psum, 32);
    f32x16 s;
#pragma unroll
    for (int r = 0; r < 16; ++r) s[r] = acc0[r] + acc1[r] + acc2[r] + acc3[r];
    if (bid0 == 0) {
        float* sc = scr + t * 20;
#pragma unroll
        for (int r = 0; r < 16; ++r) sc[r] = s[r];
        sc[16] = psum;
    }
}

// ---------------- NOFRAG (adj + skeleton; const B), rep 8 ----------------
__global__ __launch_bounds__(256, 2) void attn_nofrag(
    const int* __restrict__ adj, const float* __restrict__ srcg,
    const float* __restrict__ dstg, float* __restrict__ scr)
{
    __shared__ char s_all[74240];
    GEOM
    char* awave = s_all + q * 8192;
    char* dstw  = s_all + 65536 + q * 2048;

    const float sv = srcg[b * NN + I0 + r31];
    asm volatile("s_waitcnt vmcnt(0) lgkmcnt(0)" ::: "memory");

    const char* aSrc = (const char*)adj
        + ((size_t)(b * NN + I0 + r31) * NN + q * 512) * 4 + hi * 32;
    const char* dSrc = (const char*)(dstg + (size_t)b * NN + q * 512) + l * 16;

#define ISSUE_A(ki_, sl_) {                                                   \
        const char* pa_ = aSrc + (size_t)(ki_) * 64;                          \
        gload_lds16(pa_,      awave + (sl_) * 2048 + l * 16);                 \
        gload_lds16(pa_ + 16, awave + (sl_) * 2048 + 1024 + l * 16); }

    bf16x8 cbf;
#pragma unroll
    for (int e = 0; e < 8; ++e) cbf[e] = (__bf16)1.0f;

    f32x16 acc0 = {}, acc1 = {}, acc2 = {}, acc3 = {};
    float psum = 0.f;

#pragma unroll 1
    for (int rep = 0; rep < 8; ++rep) {
        gload_lds16(dSrc,        dstw + l * 16);
        gload_lds16(dSrc + 1024, dstw + 1024 + l * 16);
        ISSUE_A(0, 0);
        ISSUE_A(1, 1);
#pragma unroll 4
        for (int kt = 0; kt < 32; ++kt) {
            const int kA = (kt + 2 < 32) ? kt + 2 : 31;
            ISSUE_A(kA, (kt + 2) & 3);
            asm volatile("s_waitcnt vmcnt(4)" ::: "memory");
            const char* asl = awave + (kt & 3) * 2048 + l * 16;
            const int4 A0 = *(const int4*)(asl);
            const int4 A1 = *(const int4*)(asl + 1024);
            const f32x4 d0 = *(const f32x4*)(dstw + kt * 64 + hi * 32);
            const f32x4 d1 = *(const f32x4*)(dstw + kt * 64 + hi * 32 + 16);
            const int   am[8] = {A0.x, A0.y, A0.z, A0.w, A1.x, A1.y, A1.z, A1.w};
            const float dv[8] = {d0[0], d0[1], d0[2], d0[3], d1[0], d1[1], d1[2], d1[3]};
            EXPB(am[e] > 0)
            acc0 = __builtin_amdgcn_mfma_f32_32x32x16_bf16(af, cbf, acc0, 0, 0, 0);
            acc1 = __builtin_amdgcn_mfma_f32_32x32x16_bf16(af, cbf, acc1, 0, 0, 0);
            acc2 = __builtin_amdgcn_mfma_f32_32x32x16_bf16(af, cbf, acc2, 0, 0, 0);
            acc3 = __builtin_amdgcn_mfma_f32_32x32x16_bf16(af, cbf, acc3, 0, 0, 0);
        }
        asm volatile("s_waitcnt vmcnt(0)" ::: "memory");
    }
#undef ISSUE_A

    psum += __shfl_xor(psum, 32);
    f32x16 s;
#pragma unroll
    for (int r = 0; r < 16; ++r) s[r] = acc0[r] + acc1[r] + acc2[r] + acc3[r];
    if (bid0 == 0) {
        float* sc = scr + t * 20;
#pragma unroll
        for (int r = 0; r < 16; ++r) sc[r] = s[r];
        sc[16] = psum;
    }
}

// ---------------- NOMEM (skeleton only: LDS dst + exp + MFMA), rep 12 ------
__global__ __launch_bounds__(256, 2) void attn_nomem(
    const float* __restrict__ srcg, const float* __restrict__ dstg,
    float* __restrict__ scr)
{
    __shared__ char s_all[74240];
    GEOM
    char* dstw = s_all + 65536 + q * 2048;

    const float sv = srcg[b * NN + I0 + r31];
    const char* dSrc = (const char*)(dstg + (size_t)b * NN + q * 512) + l * 16;
    gload_lds16(dSrc,        dstw + l * 16);
    gload_lds16(dSrc + 1024, dstw + 1024 + l * 16);
    asm volatile("s_waitcnt vmcnt(0) lgkmcnt(0)" ::: "memory");
    __syncthreads();

    bf16x8 cbf;
#pragma unroll
    for (int e = 0; e < 8; ++e) cbf[e] = (__bf16)1.0f;

    f32x16 acc0 = {}, acc1 = {}, acc2 = {}, acc3 = {};
    float psum = 0.f;

#pragma unroll 1
    for (int rep = 0; rep < 12; ++rep) {
#pragma unroll 4
        for (int kt = 0; kt < 32; ++kt) {
            const f32x4 d0 = *(const f32x4*)(dstw + kt * 64 + hi * 32);
            const f32x4 d1 = *(const f32x4*)(dstw + kt * 64 + hi * 32 + 16);
            const float dv[8] = {d0[0], d0[1], d0[2], d0[3], d1[0], d1[1], d1[2], d1[3]};
            EXPB(((kt + e) & 1))
            acc0 = __builtin_amdgcn_mfma_f32_32x32x16_bf16(af, cbf, acc0, 0, 0, 0);
            acc1 = __builtin_amdgcn_mfma_f32_32x32x16_bf16(af, cbf, acc1, 0, 0, 0);
            acc2 = __builtin_amdgcn_mfma_f32_32x32x16_bf16(af, cbf, acc2, 0, 0, 0);
            acc3 = __builtin_amdgcn_mfma_f32_32x32x16_bf16(af, cbf, acc3, 0, 0, 0);
        }
    }

    psum += __shfl_xor(psum, 32);
    f32x16 s;
#pragma unroll
    for (int r = 0; r < 16; ++r) s[r] = acc0[r] + acc1[r] + acc2[r] + acc3[r];
    if (bid0 == 0) {
        float* sc = scr + t * 20;
#pragma unroll
        for (int r = 0; r < 16; ++r) sc[r] = s[r];
        sc[16] = psum;
    }
}

// ---------------------------------------------------------------------------
extern "C" void kernel_launch(void* const* d_in, const int* in_sizes, int n_in,
                              void* d_out, int out_size, void* d_ws, size_t ws_size,
                              hipStream_t stream)
{
    const float* h   = (const float*)d_in[0];
    const int*   adj = (const int*)d_in[1];
    const float* W   = (const float*)d_in[2];
    const float* a   = (const float*)d_in[3];
    float* out = (float*)d_out;

    char* ws = (char*)d_ws;
    __bf16* fragB = (__bf16*)ws;                              // 4 MiB
    float*  srcg  = (float*)(ws + (4 << 20));                 // 64 KiB
    float*  dstg  = (float*)(ws + (4 << 20) + (64 << 10));    // 64 KiB
    float*  scr   = (float*)(ws + (4 << 20) + (128 << 10));   // ablation scratch

    wh_kernel<<<512, 256, 0, stream>>>(h, W, a, fragB, srcg, dstg);
    attn_full<<<512, 256, 0, stream>>>(adj, fragB, srcg, dstg, out);

    if (ws_size >= (size_t)(4 << 20) + (256 << 10)) {   // diagnostics
        attn_noadj <<<512, 256, 0, stream>>>(fragB, srcg, dstg, scr);
        attn_nofrag<<<512, 256, 0, stream>>>(adj, srcg, dstg, scr + 6144);
        attn_nomem <<<512, 256, 0, stream>>>(srcg, dstg, scr + 12288);
    }
}

// Round 14
// 39.829 us; speedup vs baseline: 11.5413x; 11.5413x over previous
//
#include <hip/hip_runtime.h>
#include <hip/hip_bf16.h>

#define BB 8
#define NN 2048
#define FF 128

typedef __bf16 bf16x8 __attribute__((ext_vector_type(8)));
typedef float f32x4 __attribute__((ext_vector_type(4)));
typedef float f32x16 __attribute__((ext_vector_type(16)));

__device__ __forceinline__ void gload_lds16(const void* g, void* l) {
    __builtin_amdgcn_global_load_lds(
        (const __attribute__((address_space(1))) unsigned int*)g,
        (__attribute__((address_space(3))) unsigned int*)l, 16, 0, 0);
}

// ---------------------------------------------------------------------------
// Kernel A v13: W staged ONCE into LDS as bf16 TRANSPOSED [c][k] (pad 136)
// -> each B-frag read is a single ds_read_b128 (was 128 scalar global loads
// per thread). Everything else unchanged (refcheck-proven).
// ---------------------------------------------------------------------------
__global__ __launch_bounds__(256) void wh_kernel(
    const float* __restrict__ h, const float* __restrict__ W,
    const float* __restrict__ a, __bf16* __restrict__ fragB,
    float* __restrict__ srcg, float* __restrict__ dstg)
{
    __shared__ float  s_h[32][132];
    __shared__ __bf16 s_wh[32][132];
    __shared__ __bf16 s_Wt[128][136];   // W^T in bf16; 272B row stride
    __shared__ float  s_s[2][32];
    __shared__ float  s_d[2][32];

    const int bid = blockIdx.x;
    const int b   = bid >> 6;
    const int J   = bid & 63;
    const int r0  = J * 32;
    const int t   = threadIdx.x;
    const int w   = t >> 6;
    const int l   = t & 63;
    const int itile = w & 1;
    const int fh    = w >> 1;
    const int g     = l >> 4;
    const int c16   = l & 15;

    // h tile -> LDS (coalesced)
#pragma unroll
    for (int i = 0; i < 4; ++i) {
        const int idx = t + i * 256;
        const int r   = idx >> 5;
        const int c4  = idx & 31;
        *(f32x4*)&s_h[r][c4 * 4] =
            *(const f32x4*)(h + (size_t)(b * NN + r0 + r) * FF + c4 * 4);
    }
    // W -> LDS transposed bf16: thread t covers row wk, cols wc0..wc0+63
    {
        const int wk  = t >> 1;
        const int wc0 = (t & 1) * 64;
        const float* wrow = W + wk * FF + wc0;
#pragma unroll
        for (int i = 0; i < 16; ++i) {
            const f32x4 v = *(const f32x4*)(wrow + i * 4);
            s_Wt[wc0 + i * 4 + 0][wk] = (__bf16)v[0];
            s_Wt[wc0 + i * 4 + 1][wk] = (__bf16)v[1];
            s_Wt[wc0 + i * 4 + 2][wk] = (__bf16)v[2];
            s_Wt[wc0 + i * 4 + 3][wk] = (__bf16)v[3];
        }
    }
    __syncthreads();

    const float* hrow = &s_h[itile * 16 + c16][0];
    f32x4 acc[4] = {};

#pragma unroll
    for (int kt = 0; kt < 4; ++kt) {
        const int k0 = kt * 32 + g * 8;
        f32x4 h0 = *(const f32x4*)(hrow + k0);
        f32x4 h1 = *(const f32x4*)(hrow + k0 + 4);
        bf16x8 af;
        af[0]=(__bf16)h0[0]; af[1]=(__bf16)h0[1]; af[2]=(__bf16)h0[2]; af[3]=(__bf16)h0[3];
        af[4]=(__bf16)h1[0]; af[5]=(__bf16)h1[1]; af[6]=(__bf16)h1[2]; af[7]=(__bf16)h1[3];
#pragma unroll
        for (int ft = 0; ft < 4; ++ft) {
            const int c = (fh * 4 + ft) * 16 + c16;
            const bf16x8 bf = *(const bf16x8*)&s_Wt[c][k0];   // one b128 read
            acc[ft] = __builtin_amdgcn_mfma_f32_16x16x32_bf16(af, bf, acc[ft], 0, 0, 0);
        }
    }

    float a1v[4], a2v[4];
#pragma unroll
    for (int ft = 0; ft < 4; ++ft) {
        const int c = (fh * 4 + ft) * 16 + c16;
        a1v[ft] = a[c];
        a2v[ft] = a[FF + c];
    }
#pragma unroll
    for (int r = 0; r < 4; ++r) {
        float s = 0.f, d2 = 0.f;
#pragma unroll
        for (int ft = 0; ft < 4; ++ft) {
            s  += acc[ft][r] * a1v[ft];
            d2 += acc[ft][r] * a2v[ft];
        }
#pragma unroll
        for (int m = 1; m <= 8; m <<= 1) {
            s  += __shfl_xor(s,  m);
            d2 += __shfl_xor(d2, m);
        }
        if (c16 == 0) {
            s_s[fh][itile * 16 + g * 4 + r] = s;
            s_d[fh][itile * 16 + g * 4 + r] = d2;
        }
    }

#pragma unroll
    for (int ft = 0; ft < 4; ++ft)
#pragma unroll
        for (int r = 0; r < 4; ++r)
            s_wh[itile * 16 + g * 4 + r][(fh * 4 + ft) * 16 + c16] = (__bf16)acc[ft][r];

    __syncthreads();

    // re-read in 32x32 B-fragment order and store (16B per lane, coalesced)
#pragma unroll
    for (int e2 = 0; e2 < 2; ++e2) {
        const int ent  = t + e2 * 256;
        const int tile = ent >> 6;
        const int jl   = tile >> 2;
        const int ft   = tile & 3;
        const int lE   = ent & 63;
        const int rowE = jl * 16 + (lE >> 5) * 8;
        const int colE = ft * 32 + (lE & 31);
        bf16x8 v;
#pragma unroll
        for (int ee = 0; ee < 8; ++ee) v[ee] = s_wh[rowE + ee][colE];
        *(bf16x8*)(fragB + (((size_t)(b * 128 + J * 2 + jl) * 4 + ft) * 64 + lE) * 8) = v;
    }

    if (t < 32) {
        srcg[b * NN + r0 + t] = s_s[0][t] + s_s[1][t];
        dstg[b * NN + r0 + t] = s_d[0][t] + s_d[1][t];
    }
}

// ---------------------------------------------------------------------------
// Kernel B v13: v12's contiguous adj staging + CORRECT cross-wave sync.
// 16 steps x 128-j window; adj staged [32 rows][512B]/step, DEPTH-4 slots
// (WAR-safe: writer targets (w+2)&3 while slowest reader uses w&3).
// Per step: issue F(w+1)[8 asm reg loads] + A(w+1)[4 DMA];
//   s_waitcnt vmcnt(12)  -> own {F(w),A(w)} retired;
//   sched_barrier(0)     -> MFMA can't hoist above the wait (rule 18);
//   s_barrier            -> ALL waves' A(w) retired (T3/T4 pattern).
// Waves K-split in-window (wave q: j-offset q*32, two K=16 slices).
// Source chunk-XOR swizzle (rule 21) keeps readback effectively conflict-free.
// ---------------------------------------------------------------------------
__global__ __launch_bounds__(256, 2) void attn_kernel(
    const int* __restrict__ adj, const __bf16* __restrict__ fragB,
    const float* __restrict__ srcg, const float* __restrict__ dstg,
    float* __restrict__ out)
{
    __shared__ char s_all[74240];
    // [0,65536):      adj 4 slots x 16 KB = [32 rows][512 B], chunk-swizzled
    // [65536,73728):  dst 8 KB (f32[2048], staged cooperatively)
    // [73728,74240):  s_ps
    // tail combine reuses [0,34816)

    const int bid0 = blockIdx.x;
    const int bid  = (bid0 & 7) * 64 + (bid0 >> 3);   // bijective XCD swizzle
    const int b    = bid >> 6;
    const int I0   = (bid & 63) * 32;
    const int t    = threadIdx.x;
    const int q    = t >> 6;                  // wave = K-offset q*32 in window
    const int l    = t & 63;
    const int r31  = l & 31;
    const int hi   = l >> 5;
    const int xr   = l & 7;                   // read-side swizzle key (row&7)

    float* dstf = (float*)(s_all + 65536);
    float* s_ps = (float*)(s_all + 73728);

    // ---- plain src load, fully drained BEFORE the DMA ledger starts ----
    const float sv = srcg[b * NN + I0 + r31];
    asm volatile("s_waitcnt vmcnt(0) lgkmcnt(0)" ::: "memory");

    const char* adjBB = (const char*)adj + (size_t)b * NN * (NN * 4);
    // op o covers rows 2*(q*4+o)+hi; lane: 16B-chunk (r31 ^ (row&7)) of the
    // row's 512-B step window -> LDS row r at r*512, chunk c at (c^(r&7))*16.
    const int ro0 = 2 * (q * 4 + 0) + hi;
    const int ro1 = 2 * (q * 4 + 1) + hi;
    const int ro2 = 2 * (q * 4 + 2) + hi;
    const int ro3 = 2 * (q * 4 + 3) + hi;
    const char* aB0 = adjBB + (size_t)(I0 + ro0) * (NN * 4) + ((r31 ^ (ro0 & 7)) * 16);
    const char* aB1 = adjBB + (size_t)(I0 + ro1) * (NN * 4) + ((r31 ^ (ro1 & 7)) * 16);
    const char* aB2 = adjBB + (size_t)(I0 + ro2) * (NN * 4) + ((r31 ^ (ro2 & 7)) * 16);
    const char* aB3 = adjBB + (size_t)(I0 + ro3) * (NN * 4) + ((r31 ^ (ro3 & 7)) * 16);
    // frag: T = (b*128 + w*8 + q*2 + s)*4 + ft, addr = T*1024 + l*16
    const char* fB = (const char*)fragB + ((size_t)(b * 128 + q * 2) * 4096)
                     + (size_t)l * 16;
    const char* dS = (const char*)(dstg + (size_t)b * NN) + q * 2048 + l * 16;

#define ISSUE_A(w_, sl_) {                                                    \
        const size_t wo_ = (size_t)(w_) * 512;                                \
        char* ds_ = s_all + (sl_) * 16384 + q * 4096 + l * 16;                \
        gload_lds16(aB0 + wo_, ds_);                                          \
        gload_lds16(aB1 + wo_, ds_ + 1024);                                   \
        gload_lds16(aB2 + wo_, ds_ + 2048);                                   \
        gload_lds16(aB3 + wo_, ds_ + 3072); }

#define ISSUE_F(w_, B0_,B1_,B2_,B3_,B4_,B5_,B6_,B7_) {                        \
        const char* p0_ = fB + (size_t)(w_) * 32768;                          \
        const char* p1_ = p0_ + 4096;                                         \
        asm volatile("global_load_dwordx4 %0, %1, off"                        \
                     : "=&v"(B0_) : "v"(p0_));                                \
        asm volatile("global_load_dwordx4 %0, %1, off offset:1024"            \
                     : "=&v"(B1_) : "v"(p0_));                                \
        asm volatile("global_load_dwordx4 %0, %1, off offset:2048"            \
                     : "=&v"(B2_) : "v"(p0_));                                \
        asm volatile("global_load_dwordx4 %0, %1, off offset:3072"            \
                     : "=&v"(B3_) : "v"(p0_));                                \
        asm volatile("global_load_dwordx4 %0, %1, off"                        \
                     : "=&v"(B4_) : "v"(p1_));                                \
        asm volatile("global_load_dwordx4 %0, %1, off offset:1024"            \
                     : "=&v"(B5_) : "v"(p1_));                                \
        asm volatile("global_load_dwordx4 %0, %1, off offset:2048"            \
                     : "=&v"(B6_) : "v"(p1_));                                \
        asm volatile("global_load_dwordx4 %0, %1, off offset:3072"            \
                     : "=&v"(B7_) : "v"(p1_)); }

    bf16x8 Fa0, Fa1, Fa2, Fa3, Fa4, Fa5, Fa6, Fa7;
    bf16x8 Fb0, Fb1, Fb2, Fb3, Fb4, Fb5, Fb6, Fb7;
    f32x16 acc0 = {}, acc1 = {}, acc2 = {}, acc3 = {};
    float psum = 0.f;

    // prologue ledger: dst(2) + A(0)[4] + F(0)[8] = 14 outstanding
    gload_lds16(dS,        (char*)dstf + q * 2048 + l * 16);
    gload_lds16(dS + 1024, (char*)dstf + q * 2048 + 1024 + l * 16);
    ISSUE_A(0, 0);
    ISSUE_F(0, Fa0, Fa1, Fa2, Fa3, Fa4, Fa5, Fa6, Fa7);

#define STEP(w_, C0_,C1_,C2_,C3_,C4_,C5_,C6_,C7_, N0_,N1_,N2_,N3_,N4_,N5_,N6_,N7_) { \
        const int wn_ = ((w_) + 1 < 16) ? (w_) + 1 : 15;                      \
        ISSUE_F(wn_, N0_, N1_, N2_, N3_, N4_, N5_, N6_, N7_);                 \
        ISSUE_A(wn_, wn_ & 3);                                                \
        asm volatile("s_waitcnt vmcnt(12)" ::: "memory");                     \
        __builtin_amdgcn_sched_barrier(0);                                    \
        __builtin_amdgcn_s_barrier();                                         \
        const char* as_ = s_all + ((w_) & 3) * 16384 + r31 * 512;             \
        const int cqa_ = q * 8 + hi * 2;                                      \
        const int cqb_ = cqa_ + 4;                                            \
        const int4 A00_ = *(const int4*)(as_ + ((cqa_ ^ xr) * 16));           \
        const int4 A01_ = *(const int4*)(as_ + (((cqa_ + 1) ^ xr) * 16));     \
        const int4 A10_ = *(const int4*)(as_ + ((cqb_ ^ xr) * 16));           \
        const int4 A11_ = *(const int4*)(as_ + (((cqb_ + 1) ^ xr) * 16));     \
        const float* dw_ = dstf + (w_) * 128 + q * 32 + hi * 8;               \
        const f32x4 d00_ = *(const f32x4*)(dw_);                              \
        const f32x4 d01_ = *(const f32x4*)(dw_ + 4);                          \
        const f32x4 d10_ = *(const f32x4*)(dw_ + 16);                         \
        const f32x4 d11_ = *(const f32x4*)(dw_ + 20);                         \
        const int   am0_[8] = {A00_.x, A00_.y, A00_.z, A00_.w,                \
                               A01_.x, A01_.y, A01_.z, A01_.w};               \
        const int   am1_[8] = {A10_.x, A10_.y, A10_.z, A10_.w,                \
                               A11_.x, A11_.y, A11_.z, A11_.w};               \
        const float dv0_[8] = {d00_[0], d00_[1], d00_[2], d00_[3],            \
                               d01_[0], d01_[1], d01_[2], d01_[3]};           \
        const float dv1_[8] = {d10_[0], d10_[1], d10_[2], d10_[3],            \
                               d11_[0], d11_[1], d11_[2], d11_[3]};           \
        bf16x8 af0_, af1_;                                                    \
        _Pragma("unroll")                                                     \
        for (int e = 0; e < 8; ++e) {                                         \
            float x0 = sv + dv0_[e];                                          \
            x0 = fmaxf(x0, 0.2f * x0);                                        \
            float p0 = __expf(x0);                                            \
            p0 = (am0_[e] > 0) ? p0 : 0.f;                                    \
            psum += p0;                                                       \
            af0_[e] = (__bf16)p0;                                             \
            float x1 = sv + dv1_[e];                                          \
            x1 = fmaxf(x1, 0.2f * x1);                                        \
            float p1 = __expf(x1);                                            \
            p1 = (am1_[e] > 0) ? p1 : 0.f;                                    \
            psum += p1;                                                       \
            af1_[e] = (__bf16)p1;                                             \
        }                                                                     \
        acc0 = __builtin_amdgcn_mfma_f32_32x32x16_bf16(af0_, C0_, acc0, 0, 0, 0); \
        acc1 = __builtin_amdgcn_mfma_f32_32x32x16_bf16(af0_, C1_, acc1, 0, 0, 0); \
        acc2 = __builtin_amdgcn_mfma_f32_32x32x16_bf16(af0_, C2_, acc2, 0, 0, 0); \
        acc3 = __builtin_amdgcn_mfma_f32_32x32x16_bf16(af0_, C3_, acc3, 0, 0, 0); \
        acc0 = __builtin_amdgcn_mfma_f32_32x32x16_bf16(af1_, C4_, acc0, 0, 0, 0); \
        acc1 = __builtin_amdgcn_mfma_f32_32x32x16_bf16(af1_, C5_, acc1, 0, 0, 0); \
        acc2 = __builtin_amdgcn_mfma_f32_32x32x16_bf16(af1_, C6_, acc2, 0, 0, 0); \
        acc3 = __builtin_amdgcn_mfma_f32_32x32x16_bf16(af1_, C7_, acc3, 0, 0, 0); }

    for (int w2 = 0; w2 < 16; w2 += 2) {
        STEP(w2 + 0, Fa0,Fa1,Fa2,Fa3,Fa4,Fa5,Fa6,Fa7,
                     Fb0,Fb1,Fb2,Fb3,Fb4,Fb5,Fb6,Fb7);
        STEP(w2 + 1, Fb0,Fb1,Fb2,Fb3,Fb4,Fb5,Fb6,Fb7,
                     Fa0,Fa1,Fa2,Fa3,Fa4,Fa5,Fa6,Fa7);
    }
#undef STEP
#undef ISSUE_A
#undef ISSUE_F

    asm volatile("s_waitcnt vmcnt(0) lgkmcnt(0)" ::: "memory");  // drain dummies

    // denom partial: lanes l and l^32 cover the same row, disjoint j
    psum += __shfl_xor(psum, 32);
    if (l < 32) s_ps[q * 32 + l] = psum;

    // ---- 4-way j-partial combine in two rounds (reuse pipe LDS) ----
    float* comb = (float*)s_all;              // [(p*2+f)*64+l]*17, 34816 B
    f32x16 tot;

    __syncthreads();
    {   // round 0: ft tiles 0,1
        float* c0 = comb + ((q * 2 + 0) * 64 + l) * 17;
        float* c1 = comb + ((q * 2 + 1) * 64 + l) * 17;
#pragma unroll
        for (int r = 0; r < 16; ++r) { c0[r] = acc0[r]; c1[r] = acc1[r]; }
    }
    __syncthreads();
    if (q < 2) {
#pragma unroll
        for (int r = 0; r < 16; ++r)
            tot[r] = comb[((0 * 2 + q) * 64 + l) * 17 + r]
                   + comb[((1 * 2 + q) * 64 + l) * 17 + r]
                   + comb[((2 * 2 + q) * 64 + l) * 17 + r]
                   + comb[((3 * 2 + q) * 64 + l) * 17 + r];
    }
    __syncthreads();
    {   // round 1: ft tiles 2,3
        float* c0 = comb + ((q * 2 + 0) * 64 + l) * 17;
        float* c1 = comb + ((q * 2 + 1) * 64 + l) * 17;
#pragma unroll
        for (int r = 0; r < 16; ++r) { c0[r] = acc2[r]; c1[r] = acc3[r]; }
    }
    __syncthreads();
    if (q >= 2) {
        const int f2 = q - 2;
#pragma unroll
        for (int r = 0; r < 16; ++r)
            tot[r] = comb[((0 * 2 + f2) * 64 + l) * 17 + r]
                   + comb[((1 * 2 + f2) * 64 + l) * 17 + r]
                   + comb[((2 * 2 + f2) * 64 + l) * 17 + r]
                   + comb[((3 * 2 + f2) * 64 + l) * 17 + r];
    }

    const float dtot = s_ps[0 * 32 + r31] + s_ps[1 * 32 + r31]
                     + s_ps[2 * 32 + r31] + s_ps[3 * 32 + r31];
    const float rin  = 1.f / dtot;

    // C layout (32x32): col = l&31, row = (r&3) + 8*(r>>2) + 4*hi
#pragma unroll
    for (int r = 0; r < 16; ++r) {
        const int row  = (r & 3) + 8 * (r >> 2) + 4 * hi;
        const float dv2 = __shfl(rin, row);
        out[(size_t)(b * NN + I0 + row) * FF + q * 32 + r31] = tot[r] * dv2;
    }
}

// ---------------------------------------------------------------------------
extern "C" void kernel_launch(void* const* d_in, const int* in_sizes, int n_in,
                              void* d_out, int out_size, void* d_ws, size_t ws_size,
                              hipStream_t stream)
{
    const float* h   = (const float*)d_in[0];
    const int*   adj = (const int*)d_in[1];
    const float* W   = (const float*)d_in[2];
    const float* a   = (const float*)d_in[3];
    float* out = (float*)d_out;

    char* ws = (char*)d_ws;
    __bf16* fragB = (__bf16*)ws;                              // 4 MiB
    float*  srcg  = (float*)(ws + (4 << 20));                 // 64 KiB
    float*  dstg  = (float*)(ws + (4 << 20) + (64 << 10));    // 64 KiB

    wh_kernel<<<512, 256, 0, stream>>>(h, W, a, fragB, srcg, dstg);
    attn_kernel<<<512, 256, 0, stream>>>(adj, fragB, srcg, dstg, out);
}